// Round 1
// baseline (211.905 us; speedup 1.0000x reference)
//
#include <hip/hip_runtime.h>

#define E_EDGES 800000
#define NN 50000
#define D_IN 96
#define D_EDGE 32
#define D_OUT 96
#define KSUM 512             // 4 types x 128 feat dims
#define SSTRIDE 520          // +8 bf16 pad (row 1040 B)
#define NB4 3125             // buckets of 16 nodes (dst>>4); 3125*16 = 50000 exactly
#define ECAP 20              // per-(node,type) key capacity; Poisson(4), P(overflow)~4e-4
#define NKEYS (NB4 * 64)     // 200000 keys = bucket*64 + (dstLocal<<2|ty)
#define SCAT_BLOCKS 1024
#define BUILD_BLOCKS 512

typedef __attribute__((ext_vector_type(8))) __bf16 bf16x8;
typedef __attribute__((ext_vector_type(4))) float floatx4;

__device__ __forceinline__ float lo16(unsigned int u) {
    return __builtin_bit_cast(float, u << 16);
}
__device__ __forceinline__ float hi16(unsigned int u) {
    return __builtin_bit_cast(float, u & 0xFFFF0000u);
}
__device__ __forceinline__ unsigned int pk2(float a, float b) {
    unsigned short ua = __builtin_bit_cast(unsigned short, (__bf16)a);
    unsigned short ub = __builtin_bit_cast(unsigned short, (__bf16)b);
    return (unsigned int)ua | ((unsigned int)ub << 16);
}

// ---------- k_prep ----------
// blocks 0..SCAT_BLOCKS-1: per-edge direct key scatter (key = full (bucket,node,type))
//   -> eb arrives ALREADY (node,type)-sorted per bucket; k_fused needs no sort.
//   800K atomics over 200K counters = 4-way avg contention (vs 160-way on the old
//   3125-counter chunked scheme).
// blocks SCAT_BLOCKS.. : bf16 xeb table + WT transpose (unchanged).
__global__ __launch_bounds__(256) void k_prep(const int* __restrict__ ei,
                                              const int* __restrict__ et,
                                              const float* __restrict__ x,
                                              const float* __restrict__ ef,
                                              const float* __restrict__ Wm,
                                              int* __restrict__ cursor,
                                              int* __restrict__ eb,
                                              __bf16* __restrict__ WT,
                                              unsigned int* __restrict__ xeb) {
    int tid = threadIdx.x, bid = blockIdx.x;

    if (bid < SCAT_BLOCKS) {
        for (int e = bid * 256 + tid; e < E_EDGES; e += SCAT_BLOCKS * 256) {
            int dst = ei[E_EDGES + e];
            int ty  = et[e];
            int src = ei[e];
            int key = ((dst >> 4) << 6) | ((dst & 15) << 2) | ty;
            int r = atomicAdd(&cursor[key], 1);
            if (r < ECAP) eb[key * ECAP + r] = src << 6;   // payload = src pre-shifted
        }
    } else {
        int b2 = bid - SCAT_BLOCKS;
        int gtid = b2 * 256 + tid;
        int lane = tid & 63, w = tid >> 6;
        for (int n = b2 * 4 + w; n < NN; n += BUILD_BLOCKS * 4) {
            float2 v;
            if (lane < 48) v = *(const float2*)(x  + (size_t)n * D_IN   + 2 * lane);
            else           v = *(const float2*)(ef + (size_t)n * D_EDGE + 2 * (lane - 48));
            xeb[(size_t)n * 64 + lane] = pk2(v.x, v.y);
        }
        for (int i = gtid; i < 96 * KSUM; i += BUILD_BLOCKS * 256) {
            int n = i >> 9, k = i & 511;
            WT[n * KSUM + k] = (__bf16)Wm[(size_t)k * 96 + n];
        }
    }
}

// ---------- k_fused: one 16-node bucket per block ----------
// Edges land pre-sorted by key, so the old histogram/scan/scatter section is gone
// (it was ~28% of VALUBusy + 983K LDS bank conflicts + 2 barriers). Phase A now
// runs TWO type-streams per node concurrently (wave-uniform guards, no divergence)
// -> 8 gathers in flight per wave instead of 4, halving exposed L2/L3 latency.
__global__ __launch_bounds__(256) void k_fused(const int* __restrict__ cursor,
                                               const int* __restrict__ eb,
                                               const unsigned int* __restrict__ xeb,
                                               const __bf16* __restrict__ WT,
                                               const float* __restrict__ bm,
                                               float* __restrict__ out) {
    __shared__ __align__(16) __bf16 Sl[16][SSTRIDE];   // 16640 B
    __shared__ __align__(16) int el[64 * ECAP];        // 5120 B, (node,type)-sorted
    __shared__ int h[64];                              // per-key counts

    int tid = threadIdx.x, lane = tid & 63, w = tid >> 6;
    int B = blockIdx.x;

    if (tid < 64) h[tid] = min(cursor[B * 64 + tid], ECAP);
    {   // stage this bucket's 64 key segments (dense 5120 B, coalesced int4)
        const int4* s4 = (const int4*)(eb + (size_t)B * (64 * ECAP));
        int4* d4 = (int4*)el;
        for (int i = tid; i < (64 * ECAP) / 4; i += 256) d4[i] = s4[i];
    }
    __syncthreads();

    unsigned int Mmask = (lane >= 48) ? 0x7FFFFFFFu : 0xFFFFFFFFu;
    int quad = lane >> 4, low = lane & 15;

#define EDGE(u, k, nn, sa, sb) do {                                            \
        float f0 = lo16(u), f1 = hi16(u);                                      \
        f0 = __builtin_bit_cast(float,                                         \
                 __builtin_bit_cast(unsigned int, f0 - e0) & Mmask);           \
        f1 = __builtin_bit_cast(float,                                         \
                 __builtin_bit_cast(unsigned int, f1 - e1) & Mmask);           \
        sa += (i + k < nn) ? f0 : 0.f;                                         \
        sb += (i + k < nn) ? f1 : 0.f;                                         \
    } while (0)

    // ---- phase A: per node, two concurrent type-streams (8 loads in flight) ----
    for (int j = 0; j < 4; j++) {
        int nl = w * 4 + j;                  // node-local 0..15, Sl row
        int n = B * 16 + nl;                 // global node (< 50000 always)
        float e0 = 0.f, e1 = 0.f;
        if (lane >= 48) {
            unsigned int u = xeb[(size_t)n * 64 + lane];   // dst's own ef pair
            e0 = lo16(u); e1 = hi16(u);
        }
        unsigned int* sp = (unsigned int*)&Sl[nl][0];

#pragma unroll
        for (int tp = 0; tp < 2; tp++) {
            int k0 = nl * 4 + 2 * tp;
            int n0 = h[k0], n1 = h[k0 + 1];  // wave-uniform
            const int* q0 = el + k0 * ECAP;
            const int* q1 = q0 + ECAP;
            float sa0 = 0.f, sb0 = 0.f, sa1 = 0.f, sb1 = 0.f;
            int mx = max(n0, n1);
            for (int i = 0; i < mx; i += 4) {
                unsigned int u0=0,u1=0,u2=0,u3=0, v0=0,v1=0,v2=0,v3=0;
                bool on0 = i < n0, on1 = i < n1;   // uniform branches
                if (on0) {
                    int4 a = *(const int4*)(q0 + i);
                    int a1 = (i + 1 < n0) ? a.y : a.x;   // clamp pads to slot 0
                    int a2 = (i + 2 < n0) ? a.z : a.x;   // (L1-hot dup, garbage-safe)
                    int a3 = (i + 3 < n0) ? a.w : a.x;
                    u0 = xeb[a.x + lane]; u1 = xeb[a1 + lane];
                    u2 = xeb[a2 + lane]; u3 = xeb[a3 + lane];
                }
                if (on1) {
                    int4 b = *(const int4*)(q1 + i);
                    int b1 = (i + 1 < n1) ? b.y : b.x;
                    int b2 = (i + 2 < n1) ? b.z : b.x;
                    int b3 = (i + 3 < n1) ? b.w : b.x;
                    v0 = xeb[b.x + lane]; v1 = xeb[b1 + lane];
                    v2 = xeb[b2 + lane]; v3 = xeb[b3 + lane];
                }
                if (on0) { EDGE(u0,0,n0,sa0,sb0); EDGE(u1,1,n0,sa0,sb0);
                           EDGE(u2,2,n0,sa0,sb0); EDGE(u3,3,n0,sa0,sb0); }
                if (on1) { EDGE(v0,0,n1,sa1,sb1); EDGE(v1,1,n1,sa1,sb1);
                           EDGE(v2,2,n1,sa1,sb1); EDGE(v3,3,n1,sa1,sb1); }
            }
            sp[(2 * tp) * 64 + lane]     = pk2(sa0, sb0);
            sp[(2 * tp + 1) * 64 + lane] = pk2(sa1, sb1);
        }
    }
#undef EDGE
    __syncthreads();

    // ---- phase B: 16x96 = Sl[16x512] @ WT^T; 6 col tiles over 4 waves ----
    bf16x8 a[16];                       // A: m=low, k=ks*32+quad*8+j
    const __bf16* ap = &Sl[low][0] + quad * 8;
#pragma unroll
    for (int ks = 0; ks < 16; ks++) a[ks] = *(const bf16x8*)(ap + ks * 32);

    for (int ct = w; ct < 6; ct += 4) {
        floatx4 acc = {0.f, 0.f, 0.f, 0.f};
        const __bf16* bp = WT + (size_t)(ct * 16 + low) * KSUM + quad * 8;
#pragma unroll
        for (int ks = 0; ks < 16; ks++)
            acc = __builtin_amdgcn_mfma_f32_16x16x32_bf16(
                a[ks], *(const bf16x8*)(bp + ks * 32), acc, 0, 0, 0);
        int col = ct * 16 + low;
#pragma unroll
        for (int rg = 0; rg < 4; rg++) {
            int r = quad * 4 + rg;              // C/D: row = quad*4+reg
            int g = B * 16 + r;                 // < 50000 always (3125*16)
            float bias = (float)h[r * 4 + 0] * bm[col]
                       + (float)h[r * 4 + 1] * bm[96 + col]
                       + (float)h[r * 4 + 2] * bm[192 + col]
                       + (float)h[r * 4 + 3] * bm[288 + col];
            out[(size_t)g * D_OUT + col] = 0.25f * (acc[rg] + bias);
        }
    }
}

extern "C" void kernel_launch(void* const* d_in, const int* in_sizes, int n_in,
                              void* d_out, int out_size, void* d_ws, size_t ws_size,
                              hipStream_t stream) {
    const float* x  = (const float*)d_in[0];
    const float* ef = (const float*)d_in[1];
    const int*   ei = (const int*)d_in[2];
    const int*   et = (const int*)d_in[3];
    const float* Wm = (const float*)d_in[4];
    const float* bm = (const float*)d_in[5];
    float* out = (float*)d_out;

    int* cursor = (int*)d_ws;                       // NKEYS ints (800 KB)
    int* eb     = cursor + NKEYS;                   // NKEYS*ECAP ints (16 MB)
    __bf16* WT  = (__bf16*)(eb + NKEYS * ECAP);     // 96*512 bf16 (96 KB)
    unsigned int* xeb = (unsigned int*)(WT + 96 * KSUM);   // NN*64 dwords (~12.8 MB)
    // total ws ~29.7 MB

    hipMemsetAsync(cursor, 0, NKEYS * sizeof(int), stream);
    k_prep <<<SCAT_BLOCKS + BUILD_BLOCKS, 256, 0, stream>>>(ei, et, x, ef, Wm,
                                                            cursor, eb, WT, xeb);
    k_fused<<<NB4, 256, 0, stream>>>(cursor, eb, xeb, WT, bm, out);
}

// Round 2
// 179.599 us; speedup vs baseline: 1.1799x; 1.1799x over previous
//
#include <hip/hip_runtime.h>

#define E_EDGES 800000
#define NN 50000
#define D_IN 96
#define D_EDGE 32
#define D_OUT 96
#define KSUM 512             // 4 types x 128 feat dims
#define SSTRIDE 520          // +8 bf16 pad (row 1040 B)
#define NB4 3125             // buckets of 16 nodes (dst>>4); 3125*16 = 50000 exactly
#define ECAP 20              // per-(node,type) capacity; Poisson(4), P(any>20)~1e-5
#define NKEYS 200000         // key = dst*4 + ty
#define NBINS 196            // coarse bins of 256 nodes (dst>>8); 196*256 >= 50000
#define BINCAP 4608          // Poisson(4096) + 8 sigma
#define SCATA 200            // coarse-scatter chunk blocks
#define CHUNK 4000           // edges per chunk (200*4000 = 800000 exactly)
#define CHIT 16              // ceil(4000/256)
#define BUILD_BLOCKS 512

typedef __attribute__((ext_vector_type(8))) __bf16 bf16x8;
typedef __attribute__((ext_vector_type(4))) float floatx4;

__device__ __forceinline__ float lo16(unsigned int u) {
    return __builtin_bit_cast(float, u << 16);
}
__device__ __forceinline__ float hi16(unsigned int u) {
    return __builtin_bit_cast(float, u & 0xFFFF0000u);
}
__device__ __forceinline__ unsigned int pk2(float a, float b) {
    unsigned short ua = __builtin_bit_cast(unsigned short, (__bf16)a);
    unsigned short ub = __builtin_bit_cast(unsigned short, (__bf16)b);
    return (unsigned int)ua | ((unsigned int)ub << 16);
}

// ---------- kA: coarse radix pass + table build ----------
// blocks 0..SCATA-1: chunk of 4000 edges -> LDS-sorted by coarse bin (dst>>8),
//   bulk-reserved (196 global atomics/block, 39K total vs 800K direct), written
//   as COALESCED ~80B runs into CA. Record u32 = src<<10 | (dst&255)<<2 | ty.
// blocks SCATA.. : bf16 xeb table + WT transpose (unchanged).
__global__ __launch_bounds__(256) void k_prep(const int* __restrict__ ei,
                                              const int* __restrict__ et,
                                              const float* __restrict__ x,
                                              const float* __restrict__ ef,
                                              const float* __restrict__ Wm,
                                              int* __restrict__ ccnt,
                                              int* __restrict__ CA,
                                              __bf16* __restrict__ WT,
                                              unsigned int* __restrict__ xeb) {
    __shared__ int h[NBINS], base[NBINS], c2[NBINS], gb[NBINS];
    __shared__ uint2 stage[CHUNK];          // 32 KB
    int tid = threadIdx.x, bid = blockIdx.x;

    if (bid < SCATA) {
        int e0 = bid * CHUNK;
        for (int i = tid; i < NBINS; i += 256) h[i] = 0;
        __syncthreads();

        unsigned int rec[CHIT];
        int bn[CHIT];
#pragma unroll
        for (int it = 0; it < CHIT; it++) {
            int i = it * 256 + tid;
            bn[it] = -1;
            if (i < CHUNK) {
                int e = e0 + i;
                int dst = ei[E_EDGES + e];
                int ty  = et[e];
                int src = ei[e];
                rec[it] = ((unsigned)src << 10) | ((unsigned)(dst & 255) << 2)
                        | (unsigned)ty;
                int b = dst >> 8;
                bn[it] = b;
                atomicAdd(&h[b], 1);        // LDS histogram
            }
        }
        __syncthreads();

        // exclusive scan over 196 bins: single wave, shuffle-only
        if (tid < 64) {
            int lane = tid, carry = 0;
            for (int s = 0; s < NBINS; s += 64) {
                int idx = s + lane;
                int v = (idx < NBINS) ? h[idx] : 0;
                int sc = v;
                for (int d = 1; d < 64; d <<= 1) {
                    int t = __shfl_up(sc, d, 64);
                    if (lane >= d) sc += t;
                }
                if (idx < NBINS) { base[idx] = carry + sc - v; c2[idx] = carry + sc - v; }
                carry += __shfl(sc, 63, 64);
            }
        }
        __syncthreads();

        // local rank + stage into bin-sorted LDS order
#pragma unroll
        for (int it = 0; it < CHIT; it++) {
            if (bn[it] >= 0) {
                int pos = atomicAdd(&c2[bn[it]], 1);
                stage[pos] = make_uint2(rec[it], (unsigned)bn[it]);
            }
        }
        // bulk reservation (independent of stage fill; both fence at next barrier)
        for (int b = tid; b < NBINS; b += 256)
            gb[b] = h[b] ? atomicAdd(&ccnt[b], h[b]) : 0;
        __syncthreads();

        // coalesced run write-out: consecutive i within a bin -> consecutive addrs
        for (int i = tid; i < CHUNK; i += 256) {
            uint2 s = stage[i];
            int b = (int)s.y;
            int pos = gb[b] + (i - base[b]);
            if (pos < BINCAP) CA[b * BINCAP + pos] = (int)s.x;
        }
    } else {
        int b2 = bid - SCATA;
        int gtid = b2 * 256 + tid;
        int lane = tid & 63, w = tid >> 6;
        for (int n = b2 * 4 + w; n < NN; n += BUILD_BLOCKS * 4) {
            float2 v;
            if (lane < 48) v = *(const float2*)(x  + (size_t)n * D_IN   + 2 * lane);
            else           v = *(const float2*)(ef + (size_t)n * D_EDGE + 2 * (lane - 48));
            xeb[(size_t)n * 64 + lane] = pk2(v.x, v.y);
        }
        for (int i = gtid; i < 96 * KSUM; i += BUILD_BLOCKS * 256) {
            int n = i >> 9, k = i & 511;
            WT[n * KSUM + k] = (__bf16)Wm[(size_t)k * 96 + n];
        }
    }
}

// ---------- kB: fine pass, one coarse bin per block ----------
// Bin's 1024 keys -> LDS counters (lambda=4, no contention); payload scatter
// lands in the bin's PRIVATE 80 KB eb window (write-allocate lines fetched once,
// L2-local to this block). Counts written coalesced; replaces the 800 KB memset.
__global__ __launch_bounds__(256) void k_bin(const int* __restrict__ ccnt,
                                             const int* __restrict__ CA,
                                             int* __restrict__ cnt,
                                             int* __restrict__ eb) {
    __shared__ int kcnt[1024];
    int tid = threadIdx.x, c = blockIdx.x;
    for (int i = tid; i < 1024; i += 256) kcnt[i] = 0;
    __syncthreads();

    int m = min(ccnt[c], BINCAP);
    const int* src = CA + c * BINCAP;
    for (int i = tid; i < m; i += 256) {
        unsigned int r = (unsigned)src[i];           // coalesced
        int lk = (int)((r >> 2) & 255) * 4 + (int)(r & 3);
        int rk = atomicAdd(&kcnt[lk], 1);
        int key = c * 1024 + lk;                     // == dst*4 + ty
        if (rk < ECAP && key < NKEYS)
            eb[key * ECAP + rk] = (int)(r >> 10) << 6;   // payload = src<<6
    }
    __syncthreads();
    for (int lk = tid; lk < 1024; lk += 256) {
        int key = c * 1024 + lk;
        if (key < NKEYS) cnt[key] = kcnt[lk];
    }
}

// ---------- k_fused: BYTE-IDENTICAL to round 1 ----------
__global__ __launch_bounds__(256) void k_fused(const int* __restrict__ cursor,
                                               const int* __restrict__ eb,
                                               const unsigned int* __restrict__ xeb,
                                               const __bf16* __restrict__ WT,
                                               const float* __restrict__ bm,
                                               float* __restrict__ out) {
    __shared__ __align__(16) __bf16 Sl[16][SSTRIDE];   // 16640 B
    __shared__ __align__(16) int el[64 * ECAP];        // 5120 B, (node,type)-sorted
    __shared__ int h[64];                              // per-key counts

    int tid = threadIdx.x, lane = tid & 63, w = tid >> 6;
    int B = blockIdx.x;

    if (tid < 64) h[tid] = min(cursor[B * 64 + tid], ECAP);
    {   // stage this bucket's 64 key segments (dense 5120 B, coalesced int4)
        const int4* s4 = (const int4*)(eb + (size_t)B * (64 * ECAP));
        int4* d4 = (int4*)el;
        for (int i = tid; i < (64 * ECAP) / 4; i += 256) d4[i] = s4[i];
    }
    __syncthreads();

    unsigned int Mmask = (lane >= 48) ? 0x7FFFFFFFu : 0xFFFFFFFFu;
    int quad = lane >> 4, low = lane & 15;

#define EDGE(u, k, nn, sa, sb) do {                                            \
        float f0 = lo16(u), f1 = hi16(u);                                      \
        f0 = __builtin_bit_cast(float,                                         \
                 __builtin_bit_cast(unsigned int, f0 - e0) & Mmask);           \
        f1 = __builtin_bit_cast(float,                                         \
                 __builtin_bit_cast(unsigned int, f1 - e1) & Mmask);           \
        sa += (i + k < nn) ? f0 : 0.f;                                         \
        sb += (i + k < nn) ? f1 : 0.f;                                         \
    } while (0)

    // ---- phase A: per node, two concurrent type-streams (8 loads in flight) ----
    for (int j = 0; j < 4; j++) {
        int nl = w * 4 + j;                  // node-local 0..15, Sl row
        int n = B * 16 + nl;                 // global node (< 50000 always)
        float e0 = 0.f, e1 = 0.f;
        if (lane >= 48) {
            unsigned int u = xeb[(size_t)n * 64 + lane];   // dst's own ef pair
            e0 = lo16(u); e1 = hi16(u);
        }
        unsigned int* sp = (unsigned int*)&Sl[nl][0];

#pragma unroll
        for (int tp = 0; tp < 2; tp++) {
            int k0 = nl * 4 + 2 * tp;
            int n0 = h[k0], n1 = h[k0 + 1];  // wave-uniform
            const int* q0 = el + k0 * ECAP;
            const int* q1 = q0 + ECAP;
            float sa0 = 0.f, sb0 = 0.f, sa1 = 0.f, sb1 = 0.f;
            int mx = max(n0, n1);
            for (int i = 0; i < mx; i += 4) {
                unsigned int u0=0,u1=0,u2=0,u3=0, v0=0,v1=0,v2=0,v3=0;
                bool on0 = i < n0, on1 = i < n1;   // uniform branches
                if (on0) {
                    int4 a = *(const int4*)(q0 + i);
                    int a1 = (i + 1 < n0) ? a.y : a.x;   // clamp pads to slot 0
                    int a2 = (i + 2 < n0) ? a.z : a.x;   // (L1-hot dup, garbage-safe)
                    int a3 = (i + 3 < n0) ? a.w : a.x;
                    u0 = xeb[a.x + lane]; u1 = xeb[a1 + lane];
                    u2 = xeb[a2 + lane]; u3 = xeb[a3 + lane];
                }
                if (on1) {
                    int4 b = *(const int4*)(q1 + i);
                    int b1 = (i + 1 < n1) ? b.y : b.x;
                    int b2 = (i + 2 < n1) ? b.z : b.x;
                    int b3 = (i + 3 < n1) ? b.w : b.x;
                    v0 = xeb[b.x + lane]; v1 = xeb[b1 + lane];
                    v2 = xeb[b2 + lane]; v3 = xeb[b3 + lane];
                }
                if (on0) { EDGE(u0,0,n0,sa0,sb0); EDGE(u1,1,n0,sa0,sb0);
                           EDGE(u2,2,n0,sa0,sb0); EDGE(u3,3,n0,sa0,sb0); }
                if (on1) { EDGE(v0,0,n1,sa1,sb1); EDGE(v1,1,n1,sa1,sb1);
                           EDGE(v2,2,n1,sa1,sb1); EDGE(v3,3,n1,sa1,sb1); }
            }
            sp[(2 * tp) * 64 + lane]     = pk2(sa0, sb0);
            sp[(2 * tp + 1) * 64 + lane] = pk2(sa1, sb1);
        }
    }
#undef EDGE
    __syncthreads();

    // ---- phase B: 16x96 = Sl[16x512] @ WT^T; 6 col tiles over 4 waves ----
    bf16x8 a[16];                       // A: m=low, k=ks*32+quad*8+j
    const __bf16* ap = &Sl[low][0] + quad * 8;
#pragma unroll
    for (int ks = 0; ks < 16; ks++) a[ks] = *(const bf16x8*)(ap + ks * 32);

    for (int ct = w; ct < 6; ct += 4) {
        floatx4 acc = {0.f, 0.f, 0.f, 0.f};
        const __bf16* bp = WT + (size_t)(ct * 16 + low) * KSUM + quad * 8;
#pragma unroll
        for (int ks = 0; ks < 16; ks++)
            acc = __builtin_amdgcn_mfma_f32_16x16x32_bf16(
                a[ks], *(const bf16x8*)(bp + ks * 32), acc, 0, 0, 0);
        int col = ct * 16 + low;
#pragma unroll
        for (int rg = 0; rg < 4; rg++) {
            int r = quad * 4 + rg;              // C/D: row = quad*4+reg
            int g = B * 16 + r;                 // < 50000 always (3125*16)
            float bias = (float)h[r * 4 + 0] * bm[col]
                       + (float)h[r * 4 + 1] * bm[96 + col]
                       + (float)h[r * 4 + 2] * bm[192 + col]
                       + (float)h[r * 4 + 3] * bm[288 + col];
            out[(size_t)g * D_OUT + col] = 0.25f * (acc[rg] + bias);
        }
    }
}

extern "C" void kernel_launch(void* const* d_in, const int* in_sizes, int n_in,
                              void* d_out, int out_size, void* d_ws, size_t ws_size,
                              hipStream_t stream) {
    const float* x  = (const float*)d_in[0];
    const float* ef = (const float*)d_in[1];
    const int*   ei = (const int*)d_in[2];
    const int*   et = (const int*)d_in[3];
    const float* Wm = (const float*)d_in[4];
    const float* bm = (const float*)d_in[5];
    float* out = (float*)d_out;

    int* ccnt = (int*)d_ws;                        // 256 ints (NBINS used)
    int* cnt  = ccnt + 256;                        // NKEYS ints (800 KB, no memset)
    int* CA   = cnt + NKEYS;                       // NBINS*BINCAP ints (3.6 MB)
    int* eb   = CA + NBINS * BINCAP;               // NKEYS*ECAP ints (16 MB)
    __bf16* WT  = (__bf16*)(eb + NKEYS * ECAP);    // 96*512 bf16
    unsigned int* xeb = (unsigned int*)(WT + 96 * KSUM);   // NN*64 dwords (12.8 MB)
    // total ws ~33.3 MB

    hipMemsetAsync(ccnt, 0, NBINS * sizeof(int), stream);
    k_prep <<<SCATA + BUILD_BLOCKS, 256, 0, stream>>>(ei, et, x, ef, Wm,
                                                      ccnt, CA, WT, xeb);
    k_bin  <<<NBINS, 256, 0, stream>>>(ccnt, CA, cnt, eb);
    k_fused<<<NB4, 256, 0, stream>>>(cnt, eb, xeb, WT, bm, out);
}

// Round 3
// 179.479 us; speedup vs baseline: 1.1807x; 1.0007x over previous
//
#include <hip/hip_runtime.h>

#define E_EDGES 800000
#define NN 50000
#define D_IN 96
#define D_EDGE 32
#define D_OUT 96
#define KSUM 512             // 4 types x 128 feat dims
#define SSTRIDE 520          // +8 bf16 pad (row 1040 B)
#define NB4 3125             // buckets of 16 nodes (dst>>4); 3125*16 = 50000 exactly
#define ECAP 20              // per-(node,type) capacity; Poisson(4), P(any>20)~1e-5
#define NKEYS 200000         // key = dst*4 + ty
#define NBINS 196            // coarse bins of 256 nodes (dst>>8); 196*256 >= 50000
#define BINCAP 4608          // Poisson(4096) + 8 sigma
#define SCATA 400            // coarse-scatter chunk blocks (was 200: halve serial depth)
#define CHUNK 2000           // edges per chunk (400*2000 = 800000 exactly)
#define CHIT 8               // ceil(2000/256)
#define BUILD_BLOCKS 512

typedef __attribute__((ext_vector_type(8))) __bf16 bf16x8;
typedef __attribute__((ext_vector_type(4))) float floatx4;

__device__ __forceinline__ float lo16(unsigned int u) {
    return __builtin_bit_cast(float, u << 16);
}
__device__ __forceinline__ float hi16(unsigned int u) {
    return __builtin_bit_cast(float, u & 0xFFFF0000u);
}
__device__ __forceinline__ unsigned int pk2(float a, float b) {
    unsigned short ua = __builtin_bit_cast(unsigned short, (__bf16)a);
    unsigned short ub = __builtin_bit_cast(unsigned short, (__bf16)b);
    return (unsigned int)ua | ((unsigned int)ub << 16);
}

// ---------- k_prep: coarse radix pass + table build ----------
__global__ __launch_bounds__(256) void k_prep(const int* __restrict__ ei,
                                              const int* __restrict__ et,
                                              const float* __restrict__ x,
                                              const float* __restrict__ ef,
                                              const float* __restrict__ Wm,
                                              int* __restrict__ ccnt,
                                              int* __restrict__ CA,
                                              __bf16* __restrict__ WT,
                                              unsigned int* __restrict__ xeb) {
    __shared__ int h[NBINS], base[NBINS], c2[NBINS], gb[NBINS];
    __shared__ uint2 stage[CHUNK];          // 16 KB
    int tid = threadIdx.x, bid = blockIdx.x;

    if (bid < SCATA) {
        int e0 = bid * CHUNK;
        for (int i = tid; i < NBINS; i += 256) h[i] = 0;
        __syncthreads();

        unsigned int rec[CHIT];
        int bn[CHIT];
#pragma unroll
        for (int it = 0; it < CHIT; it++) {
            int i = it * 256 + tid;
            bn[it] = -1;
            if (i < CHUNK) {
                int e = e0 + i;
                int dst = ei[E_EDGES + e];
                int ty  = et[e];
                int src = ei[e];
                rec[it] = ((unsigned)src << 10) | ((unsigned)(dst & 255) << 2)
                        | (unsigned)ty;
                int b = dst >> 8;
                bn[it] = b;
                atomicAdd(&h[b], 1);        // LDS histogram
            }
        }
        __syncthreads();

        // exclusive scan over 196 bins: single wave, shuffle-only
        if (tid < 64) {
            int lane = tid, carry = 0;
            for (int s = 0; s < NBINS; s += 64) {
                int idx = s + lane;
                int v = (idx < NBINS) ? h[idx] : 0;
                int sc = v;
                for (int d = 1; d < 64; d <<= 1) {
                    int t = __shfl_up(sc, d, 64);
                    if (lane >= d) sc += t;
                }
                if (idx < NBINS) { base[idx] = carry + sc - v; c2[idx] = carry + sc - v; }
                carry += __shfl(sc, 63, 64);
            }
        }
        __syncthreads();

        // local rank + stage into bin-sorted LDS order
#pragma unroll
        for (int it = 0; it < CHIT; it++) {
            if (bn[it] >= 0) {
                int pos = atomicAdd(&c2[bn[it]], 1);
                stage[pos] = make_uint2(rec[it], (unsigned)bn[it]);
            }
        }
        // bulk reservation (independent of stage fill; both fence at next barrier)
        for (int b = tid; b < NBINS; b += 256)
            gb[b] = h[b] ? atomicAdd(&ccnt[b], h[b]) : 0;
        __syncthreads();

        // coalesced run write-out: consecutive i within a bin -> consecutive addrs
        for (int i = tid; i < CHUNK; i += 256) {
            uint2 s = stage[i];
            int b = (int)s.y;
            int pos = gb[b] + (i - base[b]);
            if (pos < BINCAP) CA[b * BINCAP + pos] = (int)s.x;
        }
    } else {
        int b2 = bid - SCATA;
        int gtid = b2 * 256 + tid;
        int lane = tid & 63, w = tid >> 6;
        for (int n = b2 * 4 + w; n < NN; n += BUILD_BLOCKS * 4) {
            float2 v;
            if (lane < 48) v = *(const float2*)(x  + (size_t)n * D_IN   + 2 * lane);
            else           v = *(const float2*)(ef + (size_t)n * D_EDGE + 2 * (lane - 48));
            xeb[(size_t)n * 64 + lane] = pk2(v.x, v.y);
        }
        for (int i = gtid; i < 96 * KSUM; i += BUILD_BLOCKS * 256) {
            int n = i >> 9, k = i & 511;
            WT[n * KSUM + k] = (__bf16)Wm[(size_t)k * 96 + n];
        }
    }
}

// ---------- k_bin: fine pass, one coarse bin per block ----------
// NEW: pads each (node,type) segment to a multiple of 4 with SELF-EDGES
// (src = dst). Self-pads contribute 0 on |ef_s - ef_d| lanes; the spurious
// x[dst] on x-lanes is removed in k_fused with one fma per stream. This lets
// k_fused drop ALL per-edge validity predicates and per-batch clamp selects.
__global__ __launch_bounds__(256) void k_bin(const int* __restrict__ ccnt,
                                             const int* __restrict__ CA,
                                             int* __restrict__ cnt,
                                             int* __restrict__ eb) {
    __shared__ int kcnt[1024];
    int tid = threadIdx.x, c = blockIdx.x;
    for (int i = tid; i < 1024; i += 256) kcnt[i] = 0;
    __syncthreads();

    int m = min(ccnt[c], BINCAP);
    const int* src = CA + c * BINCAP;
    for (int i = tid; i < m; i += 256) {
        unsigned int r = (unsigned)src[i];           // coalesced
        int lk = (int)((r >> 2) & 255) * 4 + (int)(r & 3);
        int rk = atomicAdd(&kcnt[lk], 1);
        int key = c * 1024 + lk;                     // == dst*4 + ty
        if (rk < ECAP && key < NKEYS)
            eb[key * ECAP + rk] = (int)(r >> 10) << 6;   // payload = src<<6
    }
    __syncthreads();
    for (int lk = tid; lk < 1024; lk += 256) {
        int key = c * 1024 + lk;
        if (key < NKEYS) {
            int kc = kcnt[lk];
            cnt[key] = kc;                           // true count (bias weights)
            int hh = min(kc, ECAP);
            int pp = (hh + 3) & ~3;                  // <= ECAP (20 % 4 == 0)
            int pv = (c * 256 + (lk >> 2)) << 6;     // self-edge: src = dst
            for (int rr = hh; rr < pp; rr++) eb[key * ECAP + rr] = pv;
        }
    }
}

// ---------- k_fused: one 16-node bucket per block ----------
// Phase A rebuilt: 4 concurrent type-streams per node (16 gathers in flight,
// was 8) and pad-free EDGE (8 VALU per feature-pair, was 12 + clamps) thanks
// to k_bin's self-edge padding. Self-pad x-contribution removed by one
// fma(-padcnt, x_dst) per stream.
__global__ __launch_bounds__(256) void k_fused(const int* __restrict__ cursor,
                                               const int* __restrict__ eb,
                                               const unsigned int* __restrict__ xeb,
                                               const __bf16* __restrict__ WT,
                                               const float* __restrict__ bm,
                                               float* __restrict__ out) {
    __shared__ __align__(16) __bf16 Sl[16][SSTRIDE];   // 16640 B
    __shared__ __align__(16) int el[64 * ECAP];        // 5120 B, (node,type)-sorted
    __shared__ int h[64];                              // per-key true counts (<=ECAP)

    int tid = threadIdx.x, lane = tid & 63, w = tid >> 6;
    int B = blockIdx.x;

    if (tid < 64) h[tid] = min(cursor[B * 64 + tid], ECAP);
    {   // stage this bucket's 64 key segments (dense 5120 B, coalesced int4)
        const int4* s4 = (const int4*)(eb + (size_t)B * (64 * ECAP));
        int4* d4 = (int4*)el;
        for (int i = tid; i < (64 * ECAP) / 4; i += 256) d4[i] = s4[i];
    }
    __syncthreads();

    unsigned int Mmask = (lane >= 48) ? 0x7FFFFFFFu : 0xFFFFFFFFu;
    int quad = lane >> 4, low = lane & 15;

#define EDGE(u, sa, sb) do {                                                   \
        float f0 = lo16(u), f1 = hi16(u);                                      \
        f0 = __builtin_bit_cast(float,                                         \
                 __builtin_bit_cast(unsigned int, f0 - e0) & Mmask);           \
        f1 = __builtin_bit_cast(float,                                         \
                 __builtin_bit_cast(unsigned int, f1 - e1) & Mmask);           \
        sa += f0; sb += f1;                                                    \
    } while (0)

    // ---- phase A: per node, FOUR concurrent type-streams ----
    for (int j = 0; j < 4; j++) {
        int nl = w * 4 + j;                  // node-local 0..15, Sl row
        int n = B * 16 + nl;                 // global node (< 50000 always)
        unsigned int up = xeb[(size_t)n * 64 + lane];  // dst's own pair (all lanes)
        float xd0 = lo16(up), xd1 = hi16(up);
        float e0 = (lane >= 48) ? xd0 : 0.f;           // ef-lanes subtract dst ef
        float e1 = (lane >= 48) ? xd1 : 0.f;
        float xc0 = (lane < 48) ? xd0 : 0.f;           // x-lanes pad correction
        float xc1 = (lane < 48) ? xd1 : 0.f;
        unsigned int* sp = (unsigned int*)&Sl[nl][0];

        int h0 = h[nl * 4 + 0], h1 = h[nl * 4 + 1];
        int h2 = h[nl * 4 + 2], h3 = h[nl * 4 + 3];
        int p0 = (h0 + 3) & ~3, p1 = (h1 + 3) & ~3;
        int p2 = (h2 + 3) & ~3, p3 = (h3 + 3) & ~3;
        const int* q0 = el + (nl * 4 + 0) * ECAP;
        const int* q1 = q0 + ECAP;
        const int* q2 = q1 + ECAP;
        const int* q3 = q2 + ECAP;
        float sa0 = 0.f, sb0 = 0.f, sa1 = 0.f, sb1 = 0.f;
        float sa2 = 0.f, sb2 = 0.f, sa3 = 0.f, sb3 = 0.f;
        int mx = max(max(p0, p1), max(p2, p3));
        for (int i = 0; i < mx; i += 4) {
            bool o0 = i < p0, o1 = i < p1, o2 = i < p2, o3 = i < p3; // uniform
            unsigned int ua0, ua1, ua2, ua3, ub0, ub1, ub2, ub3;
            unsigned int uc0, uc1, uc2, uc3, ue0, ue1, ue2, ue3;
            if (o0) { int4 a = *(const int4*)(q0 + i);
                      ua0 = xeb[a.x + lane]; ua1 = xeb[a.y + lane];
                      ua2 = xeb[a.z + lane]; ua3 = xeb[a.w + lane]; }
            if (o1) { int4 a = *(const int4*)(q1 + i);
                      ub0 = xeb[a.x + lane]; ub1 = xeb[a.y + lane];
                      ub2 = xeb[a.z + lane]; ub3 = xeb[a.w + lane]; }
            if (o2) { int4 a = *(const int4*)(q2 + i);
                      uc0 = xeb[a.x + lane]; uc1 = xeb[a.y + lane];
                      uc2 = xeb[a.z + lane]; uc3 = xeb[a.w + lane]; }
            if (o3) { int4 a = *(const int4*)(q3 + i);
                      ue0 = xeb[a.x + lane]; ue1 = xeb[a.y + lane];
                      ue2 = xeb[a.z + lane]; ue3 = xeb[a.w + lane]; }
            if (o0) { EDGE(ua0, sa0, sb0); EDGE(ua1, sa0, sb0);
                      EDGE(ua2, sa0, sb0); EDGE(ua3, sa0, sb0); }
            if (o1) { EDGE(ub0, sa1, sb1); EDGE(ub1, sa1, sb1);
                      EDGE(ub2, sa1, sb1); EDGE(ub3, sa1, sb1); }
            if (o2) { EDGE(uc0, sa2, sb2); EDGE(uc1, sa2, sb2);
                      EDGE(uc2, sa2, sb2); EDGE(uc3, sa2, sb2); }
            if (o3) { EDGE(ue0, sa3, sb3); EDGE(ue1, sa3, sb3);
                      EDGE(ue2, sa3, sb3); EDGE(ue3, sa3, sb3); }
        }
        // remove self-pad x contributions (ef-lane pad contribution is exactly 0)
        sa0 = fmaf((float)(h0 - p0), xc0, sa0); sb0 = fmaf((float)(h0 - p0), xc1, sb0);
        sa1 = fmaf((float)(h1 - p1), xc0, sa1); sb1 = fmaf((float)(h1 - p1), xc1, sb1);
        sa2 = fmaf((float)(h2 - p2), xc0, sa2); sb2 = fmaf((float)(h2 - p2), xc1, sb2);
        sa3 = fmaf((float)(h3 - p3), xc0, sa3); sb3 = fmaf((float)(h3 - p3), xc1, sb3);
        sp[0 * 64 + lane] = pk2(sa0, sb0);
        sp[1 * 64 + lane] = pk2(sa1, sb1);
        sp[2 * 64 + lane] = pk2(sa2, sb2);
        sp[3 * 64 + lane] = pk2(sa3, sb3);
    }
#undef EDGE
    __syncthreads();

    // ---- phase B: 16x96 = Sl[16x512] @ WT^T; 6 col tiles over 4 waves ----
    bf16x8 a[16];                       // A: m=low, k=ks*32+quad*8+j
    const __bf16* ap = &Sl[low][0] + quad * 8;
#pragma unroll
    for (int ks = 0; ks < 16; ks++) a[ks] = *(const bf16x8*)(ap + ks * 32);

    for (int ct = w; ct < 6; ct += 4) {
        floatx4 acc = {0.f, 0.f, 0.f, 0.f};
        const __bf16* bp = WT + (size_t)(ct * 16 + low) * KSUM + quad * 8;
#pragma unroll
        for (int ks = 0; ks < 16; ks++)
            acc = __builtin_amdgcn_mfma_f32_16x16x32_bf16(
                a[ks], *(const bf16x8*)(bp + ks * 32), acc, 0, 0, 0);
        int col = ct * 16 + low;
#pragma unroll
        for (int rg = 0; rg < 4; rg++) {
            int r = quad * 4 + rg;              // C/D: row = quad*4+reg
            int g = B * 16 + r;                 // < 50000 always (3125*16)
            float bias = (float)h[r * 4 + 0] * bm[col]
                       + (float)h[r * 4 + 1] * bm[96 + col]
                       + (float)h[r * 4 + 2] * bm[192 + col]
                       + (float)h[r * 4 + 3] * bm[288 + col];
            out[(size_t)g * D_OUT + col] = 0.25f * (acc[rg] + bias);
        }
    }
}

extern "C" void kernel_launch(void* const* d_in, const int* in_sizes, int n_in,
                              void* d_out, int out_size, void* d_ws, size_t ws_size,
                              hipStream_t stream) {
    const float* x  = (const float*)d_in[0];
    const float* ef = (const float*)d_in[1];
    const int*   ei = (const int*)d_in[2];
    const int*   et = (const int*)d_in[3];
    const float* Wm = (const float*)d_in[4];
    const float* bm = (const float*)d_in[5];
    float* out = (float*)d_out;

    int* ccnt = (int*)d_ws;                        // 256 ints (NBINS used)
    int* cnt  = ccnt + 256;                        // NKEYS ints (800 KB, no memset)
    int* CA   = cnt + NKEYS;                       // NBINS*BINCAP ints (3.6 MB)
    int* eb   = CA + NBINS * BINCAP;               // NKEYS*ECAP ints (16 MB)
    __bf16* WT  = (__bf16*)(eb + NKEYS * ECAP);    // 96*512 bf16
    unsigned int* xeb = (unsigned int*)(WT + 96 * KSUM);   // NN*64 dwords (12.8 MB)
    // total ws ~33.3 MB

    hipMemsetAsync(ccnt, 0, NBINS * sizeof(int), stream);
    k_prep <<<SCATA + BUILD_BLOCKS, 256, 0, stream>>>(ei, et, x, ef, Wm,
                                                      ccnt, CA, WT, xeb);
    k_bin  <<<NBINS, 256, 0, stream>>>(ccnt, CA, cnt, eb);
    k_fused<<<NB4, 256, 0, stream>>>(cnt, eb, xeb, WT, bm, out);
}